// Round 1
// baseline (363.772 us; speedup 1.0000x reference)
//
#include <hip/hip_runtime.h>

// Trilinear feature interpolation:
//   out[n,f] = sum_{k=0..7} clamp(coeffs[n,k],0,1) * features[corner_idx[n,k], f]
// N = 1e6 queries, V = 1e6 rows, F = 32 features.
//
// Mapping: 256-thread block handles 32 queries. Thread t -> (query q = t/8,
// feature group g = t%8, 4 floats each). Each corner gather is a float4 load;
// the 8 threads of a query cover the full 128 B feature row -> one coalesced
// 128 B transaction per (query, corner). idx/coeffs staged via LDS with one
// coalesced load per thread.

constexpr int F = 32;
constexpr int QUERIES_PER_BLOCK = 32;   // 32 queries * 8 threads = 256 threads

__global__ __launch_bounds__(256) void SPC_85469849190654_kernel(
    const float* __restrict__ coeffs,      // [N,8]
    const int*   __restrict__ corner_idx,  // [N,8]
    const float* __restrict__ features,    // [V,F]
    float*       __restrict__ out,         // [N,F]
    int N)
{
    __shared__ int   s_idx[256];
    __shared__ float s_c[256];

    const int t  = threadIdx.x;
    const int q0 = blockIdx.x * QUERIES_PER_BLOCK;

    // Stage 32 queries' (idx, coeff) pairs: one coalesced 4B load each.
    const long long load_pos = (long long)q0 * 8 + t;
    if (load_pos < (long long)N * 8) {
        s_idx[t] = corner_idx[load_pos];
        s_c[t]   = coeffs[load_pos];
    } else {
        s_idx[t] = 0;
        s_c[t]   = 0.0f;
    }
    __syncthreads();

    const int q_local = t >> 3;      // 0..31
    const int g       = t & 7;       // 0..7 (feature group of 4)
    const int n       = q0 + q_local;
    if (n >= N) return;

    float4 acc = make_float4(0.f, 0.f, 0.f, 0.f);

    #pragma unroll
    for (int k = 0; k < 8; ++k) {
        const int   idx = s_idx[(q_local << 3) + k];
        float       c   = s_c[(q_local << 3) + k];
        c = fminf(fmaxf(c, 0.0f), 1.0f);     // clamp(coeffs, 0, 1)
        const float4 f4 = *reinterpret_cast<const float4*>(
            features + (size_t)idx * F + (g << 2));
        acc.x = fmaf(c, f4.x, acc.x);
        acc.y = fmaf(c, f4.y, acc.y);
        acc.z = fmaf(c, f4.z, acc.z);
        acc.w = fmaf(c, f4.w, acc.w);
    }

    *reinterpret_cast<float4*>(out + (size_t)n * F + (g << 2)) = acc;
}

extern "C" void kernel_launch(void* const* d_in, const int* in_sizes, int n_in,
                              void* d_out, int out_size, void* d_ws, size_t ws_size,
                              hipStream_t stream) {
    const float* coeffs     = (const float*)d_in[0];   // [N,8] fp32
    const int*   corner_idx = (const int*)d_in[1];     // [N,8] int32
    const float* features   = (const float*)d_in[2];   // [V,32] fp32
    float*       out        = (float*)d_out;           // [N,32] fp32

    const int N = in_sizes[0] / 8;
    const int blocks = (N + QUERIES_PER_BLOCK - 1) / QUERIES_PER_BLOCK;

    SPC_85469849190654_kernel<<<blocks, 256, 0, stream>>>(
        coeffs, corner_idx, features, out, N);
}

// Round 2
// 361.681 us; speedup vs baseline: 1.0058x; 1.0058x over previous
//
#include <hip/hip_runtime.h>

// Trilinear feature interpolation:
//   out[n,f] = sum_{k=0..7} clamp(coeffs[n,k],0,1) * features[corner_idx[n,k], f]
// N = 1e6 queries, V = 1e6 rows, F = 32 features.
//
// Mapping: 256-thread block = 32 queries. Thread t -> (query q = t/8, feature
// group g = t%8, 4 floats). Each (query,corner) gather is one fully-used
// 128 B transaction spread across 8 lanes.
//
// Round 2 change: issue ALL 8 corner gathers into explicit float4 temps
// before any FMA (MLP 2 -> 8 per wave; round-1 codegen had VGPR_Count=28,
// i.e. the compiler serialized the loads). Coeffs are read from LDS in the
// accumulate phase to keep VGPRs under 64 (preserve 8 waves/SIMD).

constexpr int F = 32;
constexpr int QUERIES_PER_BLOCK = 32;   // 32 queries * 8 threads = 256 threads

__global__ __launch_bounds__(256) void SPC_85469849190654_kernel(
    const float* __restrict__ coeffs,      // [N,8]
    const int*   __restrict__ corner_idx,  // [N,8]
    const float* __restrict__ features,    // [V,F]
    float*       __restrict__ out,         // [N,F]
    int N)
{
    __shared__ int   s_idx[256];
    __shared__ float s_c[256];

    const int t  = threadIdx.x;
    const int q0 = blockIdx.x * QUERIES_PER_BLOCK;

    // Stage 32 queries' (idx, coeff) pairs: one coalesced 4B load each.
    const long long load_pos = (long long)q0 * 8 + t;
    if (load_pos < (long long)N * 8) {
        s_idx[t] = corner_idx[load_pos];
        s_c[t]   = coeffs[load_pos];
    } else {
        s_idx[t] = 0;
        s_c[t]   = 0.0f;
    }
    __syncthreads();

    const int q_local = t >> 3;      // 0..31
    const int g       = t & 7;       // 0..7 (feature group of 4)
    const int n       = q0 + q_local;
    if (n >= N) return;

    const int   qbase = q_local << 3;
    const float* fb   = features + (g << 2);

    // Phase 1: issue all 8 gathers back-to-back (8 loads in flight).
    const float4 f0 = *reinterpret_cast<const float4*>(fb + (size_t)s_idx[qbase + 0] * F);
    const float4 f1 = *reinterpret_cast<const float4*>(fb + (size_t)s_idx[qbase + 1] * F);
    const float4 f2 = *reinterpret_cast<const float4*>(fb + (size_t)s_idx[qbase + 2] * F);
    const float4 f3 = *reinterpret_cast<const float4*>(fb + (size_t)s_idx[qbase + 3] * F);
    const float4 f4 = *reinterpret_cast<const float4*>(fb + (size_t)s_idx[qbase + 4] * F);
    const float4 f5 = *reinterpret_cast<const float4*>(fb + (size_t)s_idx[qbase + 5] * F);
    const float4 f6 = *reinterpret_cast<const float4*>(fb + (size_t)s_idx[qbase + 6] * F);
    const float4 f7 = *reinterpret_cast<const float4*>(fb + (size_t)s_idx[qbase + 7] * F);

    // Phase 2: accumulate; coeffs pulled from LDS here (broadcast reads,
    // conflict-free) so they don't occupy VGPRs during the load burst.
    float4 acc = make_float4(0.f, 0.f, 0.f, 0.f);
    #define ACC(FK, K)                                             \
    {                                                              \
        float c = s_c[qbase + K];                                  \
        c = fminf(fmaxf(c, 0.0f), 1.0f);                           \
        acc.x = fmaf(c, FK.x, acc.x);                              \
        acc.y = fmaf(c, FK.y, acc.y);                              \
        acc.z = fmaf(c, FK.z, acc.z);                              \
        acc.w = fmaf(c, FK.w, acc.w);                              \
    }
    ACC(f0, 0) ACC(f1, 1) ACC(f2, 2) ACC(f3, 3)
    ACC(f4, 4) ACC(f5, 5) ACC(f6, 6) ACC(f7, 7)
    #undef ACC

    *reinterpret_cast<float4*>(out + (size_t)n * F + (g << 2)) = acc;
}

extern "C" void kernel_launch(void* const* d_in, const int* in_sizes, int n_in,
                              void* d_out, int out_size, void* d_ws, size_t ws_size,
                              hipStream_t stream) {
    const float* coeffs     = (const float*)d_in[0];   // [N,8] fp32
    const int*   corner_idx = (const int*)d_in[1];     // [N,8] int32
    const float* features   = (const float*)d_in[2];   // [V,32] fp32
    float*       out        = (float*)d_out;           // [N,32] fp32

    const int N = in_sizes[0] / 8;
    const int blocks = (N + QUERIES_PER_BLOCK - 1) / QUERIES_PER_BLOCK;

    SPC_85469849190654_kernel<<<blocks, 256, 0, stream>>>(
        coeffs, corner_idx, features, out, N);
}